// Round 6
// baseline (496.104 us; speedup 1.0000x reference)
//
#include <hip/hip_runtime.h>
#include <hip/hip_bf16.h>
#include <stdint.h>

// Problem constants
#define S 1024
#define DMODEL 768
#define NH 12
#define DK 64
#define BB 4
#define BH 48      // BB*NH
#define M4 4096    // BB*S

typedef __attribute__((ext_vector_type(8))) short bf16x8;
typedef __attribute__((ext_vector_type(4))) float f32x4;
typedef __attribute__((ext_vector_type(4))) _Float16 f16x4;
typedef __attribute__((ext_vector_type(8))) _Float16 f16x8;

static __device__ __forceinline__ unsigned short f2bf(float f) {
  unsigned int u = __float_as_uint(f);
  unsigned int r = u + 0x7FFFu + ((u >> 16) & 1u);   // RNE
  return (unsigned short)(r >> 16);
}
static __device__ __forceinline__ bf16x8 ldfrag(const unsigned short* p) {
  uint4 q = *reinterpret_cast<const uint4*>(p);
  return __builtin_bit_cast(bf16x8, q);
}
static __device__ __forceinline__ f16x8 ldfragh(const unsigned short* p) {
  uint4 q = *reinterpret_cast<const uint4*>(p);
  return __builtin_bit_cast(f16x8, q);
}
static __device__ __forceinline__ unsigned short h2u(_Float16 h) {
  return __builtin_bit_cast(unsigned short, h);
}

// ---------------- f32 -> bf16 elementwise convert ----------------
__global__ __launch_bounds__(256) void k_convert(const float* __restrict__ in,
                                                 unsigned short* __restrict__ out, int n4) {
  int i = blockIdx.x * 256 + threadIdx.x;
  if (i < n4) {
    float4 v = reinterpret_cast<const float4*>(in)[i];
    ushort4 o;
    o.x = f2bf(v.x); o.y = f2bf(v.y); o.z = f2bf(v.z); o.w = f2bf(v.w);
    reinterpret_cast<ushort4*>(out)[i] = o;
  }
}

// ---------------- W [k][n] f32 -> Wt [n][k] bf16 (768x768) ----------------
__global__ __launch_bounds__(256) void k_transpose(const float* w0, const float* w1, const float* w2,
                                                   unsigned short* o0, unsigned short* o1, unsigned short* o2) {
  const float* in = blockIdx.z == 0 ? w0 : (blockIdx.z == 1 ? w1 : w2);
  unsigned short* out = blockIdx.z == 0 ? o0 : (blockIdx.z == 1 ? o1 : o2);
  __shared__ float tile[32][33];
  int n0 = blockIdx.x * 32, k0 = blockIdx.y * 32;
  int tid = threadIdx.x;
  int r = tid >> 3, c = (tid & 7) * 4;
  float4 v = *reinterpret_cast<const float4*>(in + (size_t)(k0 + r) * DMODEL + n0 + c);
  tile[r][c] = v.x; tile[r][c + 1] = v.y; tile[r][c + 2] = v.z; tile[r][c + 3] = v.w;
  __syncthreads();
  ushort4 o;
  o.x = f2bf(tile[c + 0][r]);
  o.y = f2bf(tile[c + 1][r]);
  o.z = f2bf(tile[c + 2][r]);
  o.w = f2bf(tile[c + 3][r]);
  *reinterpret_cast<ushort4*>(out + (size_t)(n0 + r) * DMODEL + k0 + c) = o;
}

// ---------------- mask [BH][t][s] int32 -> bit array, direct orientation ----------------
// mp2[bh][wd=s>>5][t] bit(s&31) = mask[t][s].
__global__ __launch_bounds__(256) void k_pack(const int* __restrict__ mask,
                                              unsigned int* __restrict__ mp2) {
  int bh = blockIdx.y;
  int w = threadIdx.x >> 6, lane = threadIdx.x & 63;
  int tile = blockIdx.x * 4 + w;          // 0..255
  int ti = tile >> 4, tj = tile & 15;
  int t0 = ti * 64, s0 = tj * 64;
  const int* mb = mask + (size_t)bh * S * S;
  unsigned long long rowword = 0;
#pragma unroll 8
  for (int r = 0; r < 64; ++r) {
    int v = mb[(size_t)(t0 + r) * S + s0 + lane];
    unsigned long long b = __ballot(v != 0);
    if (lane == r) rowword = b;           // lane r holds bits over s for row t0+r
  }
  unsigned int* p2 = mp2 + (size_t)bh * 32 * S;
  p2[((s0 >> 5) + 0) * S + t0 + lane] = (unsigned int)rowword;
  p2[((s0 >> 5) + 1) * S + t0 + lane] = (unsigned int)(rowword >> 32);
}

// ---------------- 64x128-tile bf16 GEMM: C[4096x768] = A[4096x768] * Bt^T ----------------
// Grid (64,6,2) = 768 blocks -> ~4 resident blocks/CU (stall hiding).
// mode 0: writes Q/K [BH][S][DK] f16 AND transposed [BH][DK][S] f16.
// mode 1: writes f32 [4096][768] (pre-LayerNorm).
__global__ __launch_bounds__(256, 4) void k_gemm(
    int mode,
    const unsigned short* __restrict__ A0, const unsigned short* __restrict__ A1,
    const unsigned short* __restrict__ Bt0, const unsigned short* __restrict__ Bt1,
    unsigned short* __restrict__ oQ0, unsigned short* __restrict__ oQ1,
    unsigned short* __restrict__ oT0, unsigned short* __restrict__ oT1,
    float* __restrict__ oF0, float* __restrict__ oF1) {
  const unsigned short* A = blockIdx.z ? A1 : A0;
  const unsigned short* Bt = blockIdx.z ? Bt1 : Bt0;
  __shared__ __align__(16) unsigned short As[64 * 72];    // 9216 B
  __shared__ __align__(16) unsigned short Bs[128 * 72];   // 18432 B
  int tid = threadIdx.x;
  int m0 = blockIdx.x * 64, n0 = blockIdx.y * 128;
  int w = tid >> 6, lane = tid & 63, lane15 = lane & 15, quad = lane >> 4;
  int row0 = (w >> 1) * 32, col0 = (w & 1) * 64;   // wave quadrant: 32 rows x 64 cols
  f32x4 acc[2][4] = {};
  int sr = tid >> 2, sc = (tid & 3) * 16;
  const unsigned short* gA = A + (size_t)(m0 + sr) * DMODEL + sc;
  const unsigned short* gB0 = Bt + (size_t)(n0 + sr) * DMODEL + sc;
  const unsigned short* gB1 = Bt + (size_t)(n0 + 64 + sr) * DMODEL + sc;
  uint4 va0 = *reinterpret_cast<const uint4*>(gA);
  uint4 va1 = *reinterpret_cast<const uint4*>(gA + 8);
  uint4 vb[2][2];
  vb[0][0] = *reinterpret_cast<const uint4*>(gB0);
  vb[0][1] = *reinterpret_cast<const uint4*>(gB0 + 8);
  vb[1][0] = *reinterpret_cast<const uint4*>(gB1);
  vb[1][1] = *reinterpret_cast<const uint4*>(gB1 + 8);
  for (int kc = 0; kc < 12; ++kc) {
    __syncthreads();   // prior iter frag reads complete
    *reinterpret_cast<uint4*>(&As[sr * 72 + sc]) = va0;
    *reinterpret_cast<uint4*>(&As[sr * 72 + sc + 8]) = va1;
    *reinterpret_cast<uint4*>(&Bs[sr * 72 + sc]) = vb[0][0];
    *reinterpret_cast<uint4*>(&Bs[sr * 72 + sc + 8]) = vb[0][1];
    *reinterpret_cast<uint4*>(&Bs[(64 + sr) * 72 + sc]) = vb[1][0];
    *reinterpret_cast<uint4*>(&Bs[(64 + sr) * 72 + sc + 8]) = vb[1][1];
    if (kc < 11) {
      int k0 = (kc + 1) * 64;
      va0 = *reinterpret_cast<const uint4*>(gA + k0);
      va1 = *reinterpret_cast<const uint4*>(gA + k0 + 8);
      vb[0][0] = *reinterpret_cast<const uint4*>(gB0 + k0);
      vb[0][1] = *reinterpret_cast<const uint4*>(gB0 + k0 + 8);
      vb[1][0] = *reinterpret_cast<const uint4*>(gB1 + k0);
      vb[1][1] = *reinterpret_cast<const uint4*>(gB1 + k0 + 8);
    }
    __syncthreads();
#pragma unroll
    for (int ks = 0; ks < 2; ++ks) {
      int kk = ks * 32 + quad * 8;
      bf16x8 a[2], b[4];
#pragma unroll
      for (int i = 0; i < 2; ++i) a[i] = ldfrag(&As[(row0 + i * 16 + lane15) * 72 + kk]);
#pragma unroll
      for (int j = 0; j < 4; ++j) b[j] = ldfrag(&Bs[(col0 + j * 16 + lane15) * 72 + kk]);
#pragma unroll
      for (int i = 0; i < 2; ++i)
#pragma unroll
        for (int j = 0; j < 4; ++j)
          acc[i][j] = __builtin_amdgcn_mfma_f32_16x16x32_bf16(a[i], b[j], acc[i][j], 0, 0, 0);
    }
  }
  if (mode == 0) {
    unsigned short* out = blockIdx.z ? oQ1 : oQ0;
    unsigned short* outT = blockIdx.z ? oT1 : oT0;
    f16x4 iden;
#pragma unroll
    for (int i = 0; i < 4; ++i) iden[i] = (_Float16)((quad * 4 + i) == lane15 ? 1.0f : 0.0f);
    f32x4 zero4 = {};
#pragma unroll
    for (int i = 0; i < 2; ++i)
#pragma unroll
      for (int j = 0; j < 4; ++j) {
        f16x4 cf;
#pragma unroll
        for (int reg = 0; reg < 4; ++reg) cf[reg] = (_Float16)acc[i][j][reg];
        f32x4 tq = __builtin_amdgcn_mfma_f32_16x16x16f16(cf, iden, zero4, 0, 0, 0);
        {   // Qb store: tq regs = 4 consecutive d, fixed s -> ushort4
          int m = m0 + row0 + i * 16 + lane15;
          int n = n0 + col0 + j * 16 + quad * 4;
          int b = m >> 10, s = m & 1023, h = n >> 6, d = n & 63;
          ushort4 o;
          o.x = h2u((_Float16)tq[0]); o.y = h2u((_Float16)tq[1]);
          o.z = h2u((_Float16)tq[2]); o.w = h2u((_Float16)tq[3]);
          *reinterpret_cast<ushort4*>(&out[(((size_t)(b * NH + h)) * S + s) * DK + d]) = o;
        }
        {   // QT store: acc regs = 4 consecutive s, fixed d -> ushort4
          int n = n0 + col0 + j * 16 + lane15;
          int m = m0 + row0 + i * 16 + quad * 4;
          int b = m >> 10, s = m & 1023, h = n >> 6, d = n & 63;
          ushort4 o;
          o.x = h2u((_Float16)acc[i][j][0]); o.y = h2u((_Float16)acc[i][j][1]);
          o.z = h2u((_Float16)acc[i][j][2]); o.w = h2u((_Float16)acc[i][j][3]);
          *reinterpret_cast<ushort4*>(&outT[(((size_t)(b * NH + h)) * DK + d) * S + s]) = o;
        }
      }
  } else {
    float* out = blockIdx.z ? oF1 : oF0;
#pragma unroll
    for (int i = 0; i < 2; ++i)
#pragma unroll
      for (int j = 0; j < 4; ++j)
#pragma unroll
        for (int reg = 0; reg < 4; ++reg) {
          int m = m0 + row0 + i * 16 + quad * 4 + reg;
          int n = n0 + col0 + j * 16 + lane15;
          out[(size_t)m * DMODEL + n] = acc[i][j][reg];
        }
  }
}

// ---------------- fused dual-path attention: operand-swapped S^T, no P round-trip ----------------
// Block = (bh, path, 64 rows) -> grid 1536, ~4+ resident blocks/CU. Wave w owns 16 rows.
// Per 64-j chunk: stage Y [j][d] + YT [d][j] (f16) + 128 mask words.
// QK: S^T frags via mfma(A=Ychunk, B=Xfrag); exp w/o max (masked -> exact 0);
// P^T frag feeds PV (16x16x16 f16) directly. Zero P LDS round-trip.
__global__ __launch_bounds__(256, 4) void k_attn(
    const unsigned short* __restrict__ Qb, const unsigned short* __restrict__ Kb,
    const unsigned short* __restrict__ QT, const unsigned short* __restrict__ KT,
    const unsigned int* __restrict__ mp2,
    unsigned short* __restrict__ c1, unsigned short* __restrict__ c2) {
  int bh = blockIdx.y, path = blockIdx.z;
  int s0b = blockIdx.x * 64;
  const unsigned short* X = path ? Kb : Qb;
  const unsigned short* Y = path ? Qb : Kb;
  const unsigned short* YT = path ? QT : KT;
  unsigned short* outc = path ? c2 : c1;

  __shared__ __align__(16) unsigned short YS[64 * 72];    // Y chunk [j][d] f16
  __shared__ __align__(16) unsigned short YTS[64 * 72];   // YT chunk [d][j] f16
  __shared__ unsigned int MWS[128];                       // mask words for this chunk

  const unsigned short* Xb = X + (size_t)bh * S * DK;
  const unsigned short* Yb = Y + (size_t)bh * S * DK;
  const unsigned short* YTb = YT + (size_t)bh * DK * S;
  const unsigned int* mbg = mp2 + (size_t)bh * 32 * S;

  int tid = threadIdx.x;
  int w = tid >> 6, lane = tid & 63, lane15 = lane & 15, quad = lane >> 4;
  int s0w = s0b + w * 16;

  // X fragments double as MFMA B-operands (B[k=d][n=s/t]) for the swapped QK
  f16x8 xf0 = ldfragh(Xb + (size_t)(s0w + lane15) * DK + quad * 8);
  f16x8 xf1 = ldfragh(Xb + (size_t)(s0w + lane15) * DK + 32 + quad * 8);

  // staging: thread covers row sr4 (0..63), 16 cols at sc4
  int sr4 = tid >> 2, sc4 = (tid & 3) * 16;
  const unsigned short* gY = Yb + (size_t)sr4 * DK + sc4;
  const unsigned short* gYT = YTb + (size_t)sr4 * S + sc4;
  uint4 y0 = *reinterpret_cast<const uint4*>(gY);
  uint4 y1 = *reinterpret_cast<const uint4*>(gY + 8);
  uint4 t0 = *reinterpret_cast<const uint4*>(gYT);
  uint4 t1 = *reinterpret_cast<const uint4*>(gYT + 8);
  // mask-word prefetch: 128 words/chunk, laid out MWS[(row_or_t)*2 + wordsel]
  unsigned int mwv = 0;
  if (tid < 128)
    mwv = (path == 0)
        ? mbg[((size_t)((s0b >> 5) + (tid & 1))) * S + (tid >> 1)]
        : mbg[((size_t)(tid & 1)) * S + s0b + (tid >> 1)];

  f32x4 outa[4] = {};
  float lsum = 0.f;

  for (int jc = 0; jc < 16; ++jc) {
    __syncthreads();   // prior chunk frag reads complete
    *reinterpret_cast<uint4*>(&YS[sr4 * 72 + sc4]) = y0;
    *reinterpret_cast<uint4*>(&YS[sr4 * 72 + sc4 + 8]) = y1;
    *reinterpret_cast<uint4*>(&YTS[sr4 * 72 + sc4]) = t0;
    *reinterpret_cast<uint4*>(&YTS[sr4 * 72 + sc4 + 8]) = t1;
    if (tid < 128) MWS[tid] = mwv;
    {
      int jn = (jc + 1 < 16) ? (jc + 1) * 64 : jc * 64;   // clamped prefetch
      y0 = *reinterpret_cast<const uint4*>(gY + (size_t)jn * DK);
      y1 = *reinterpret_cast<const uint4*>(gY + (size_t)jn * DK + 8);
      t0 = *reinterpret_cast<const uint4*>(gYT + jn);
      t1 = *reinterpret_cast<const uint4*>(gYT + jn + 8);
      if (tid < 128)
        mwv = (path == 0)
            ? mbg[((size_t)((s0b >> 5) + (tid & 1))) * S + jn + (tid >> 1)]
            : mbg[((size_t)((jn >> 5) + (tid & 1))) * S + s0b + (tid >> 1)];
    }
    __syncthreads();   // staging visible

    // swapped QK: S^T[j][col] frags, C(row=j=quad*4+reg, col=lane15)
    f32x4 scv[4];
#pragma unroll
    for (int st = 0; st < 4; ++st) {
      f16x8 a0 = ldfragh(&YS[(st * 16 + lane15) * 72 + quad * 8]);
      f16x8 a1 = ldfragh(&YS[(st * 16 + lane15) * 72 + 32 + quad * 8]);
      f32x4 v = {};
      v = __builtin_amdgcn_mfma_f32_16x16x32_f16(a0, xf0, v, 0, 0, 0);
      v = __builtin_amdgcn_mfma_f32_16x16x32_f16(a1, xf1, v, 0, 0, 0);
      scv[st] = v;
    }
    // mask + exp; P^T frags are directly x16 A-operands
    f16x4 pfa[4];
    if (path == 0) {
      // word = MWS[j_local*2 + (w>>1)], bit = (w&1)*16 + lane15
      unsigned int sh = (unsigned)((w & 1) * 16 + lane15);
#pragma unroll
      for (int st = 0; st < 4; ++st)
#pragma unroll
        for (int reg = 0; reg < 4; ++reg) {
          unsigned int wdv = MWS[(st * 16 + quad * 4 + reg) * 2 + (w >> 1)];
          float e = __expf(scv[st][reg] * 0.125f);
          float p = ((wdv >> sh) & 1u) ? 0.f : e;
          lsum += p;
          pfa[st][reg] = (_Float16)p;
        }
    } else {
      // word = MWS[t_local*2 + (st>>1)], bit = (st&1)*16 + quad*4 + reg
      unsigned int wv0 = MWS[(w * 16 + lane15) * 2 + 0];
      unsigned int wv1 = MWS[(w * 16 + lane15) * 2 + 1];
#pragma unroll
      for (int st = 0; st < 4; ++st) {
        unsigned int wdv = (st < 2) ? wv0 : wv1;
#pragma unroll
        for (int reg = 0; reg < 4; ++reg) {
          unsigned int sh = (unsigned)((st & 1) * 16 + quad * 4 + reg);
          float e = __expf(scv[st][reg] * 0.125f);
          float p = ((wdv >> sh) & 1u) ? 0.f : e;
          lsum += p;
          pfa[st][reg] = (_Float16)p;
        }
      }
    }
    // PV: outa[dsub] += P^T_frag (A) x Y (B from YTS, b64 reads)
#pragma unroll
    for (int st = 0; st < 4; ++st)
#pragma unroll
      for (int dsub = 0; dsub < 4; ++dsub) {
        uint2 q = *reinterpret_cast<const uint2*>(&YTS[(dsub * 16 + lane15) * 72 + st * 16 + quad * 4]);
        f16x4 yb = __builtin_bit_cast(f16x4, q);
        outa[dsub] = __builtin_amdgcn_mfma_f32_16x16x16f16(pfa[st], yb, outa[dsub], 0, 0, 0);
      }
  }

  // row sums: lane holds partial for col lane15 over its j subset; reduce across quads
  lsum += __shfl_xor(lsum, 16);
  lsum += __shfl_xor(lsum, 32);
  float rinv[4];
#pragma unroll
  for (int reg = 0; reg < 4; ++reg)
    rinv[reg] = 1.0f / __shfl(lsum, quad * 4 + reg);

  int b = bh / NH, h = bh % NH;
#pragma unroll
  for (int dsub = 0; dsub < 4; ++dsub)
#pragma unroll
    for (int reg = 0; reg < 4; ++reg) {
      float v = outa[dsub][reg] * rinv[reg];
      int srow = s0w + quad * 4 + reg;
      size_t idx = ((size_t)(b * S) + srow) * DMODEL + h * DK + dsub * 16 + lane15;
      outc[idx] = f2bf(v);
    }
}

// ---------------- LayerNorm over 768, one block per row ----------------
__global__ __launch_bounds__(256) void k_ln(const float* __restrict__ f1, const float* __restrict__ f2,
                                            const float* __restrict__ g1, const float* __restrict__ b1,
                                            const float* __restrict__ g2, const float* __restrict__ b2,
                                            float* __restrict__ out) {
  int rowg = blockIdx.x;
  int sel = rowg >> 12;
  int row = rowg & 4095;
  const float* in = sel ? f2 : f1;
  const float* g = sel ? g2 : g1;
  const float* be = sel ? b2 : b1;
  int tid = threadIdx.x;
  const float* p = in + (size_t)row * DMODEL;
  float x0 = p[tid], x1 = p[tid + 256], x2 = p[tid + 512];
  float s = x0 + x1 + x2;
  float ss = x0 * x0 + x1 * x1 + x2 * x2;
#pragma unroll
  for (int m = 1; m < 64; m <<= 1) { s += __shfl_xor(s, m); ss += __shfl_xor(ss, m); }
  __shared__ float ps[4], pss[4];
  int w = tid >> 6;
  if ((tid & 63) == 0) { ps[w] = s; pss[w] = ss; }
  __syncthreads();
  s = ps[0] + ps[1] + ps[2] + ps[3];
  ss = pss[0] + pss[1] + pss[2] + pss[3];
  float mu = s * (1.0f / 768.0f);
  float var = ss * (1.0f / 768.0f) - mu * mu;
  float rstd = rsqrtf(var + 1e-5f);
  float* o = out + ((size_t)sel * M4 + row) * DMODEL;
  o[tid] = (x0 - mu) * rstd * g[tid] + be[tid];
  o[tid + 256] = (x1 - mu) * rstd * g[tid + 256] + be[tid + 256];
  o[tid + 512] = (x2 - mu) * rstd * g[tid + 512] + be[tid + 512];
}

extern "C" void kernel_launch(void* const* d_in, const int* in_sizes, int n_in,
                              void* d_out, int out_size, void* d_ws, size_t ws_size,
                              hipStream_t stream) {
  const float* pro1 = (const float*)d_in[0];
  const float* pro2 = (const float*)d_in[1];
  const int* mask = (const int*)d_in[2];
  const float* WQ = (const float*)d_in[3];
  const float* WK = (const float*)d_in[4];
  const float* FC1 = (const float*)d_in[5];
  const float* g1 = (const float*)d_in[6];
  const float* b1 = (const float*)d_in[7];
  const float* g2 = (const float*)d_in[8];
  const float* b2 = (const float*)d_in[9];
  float* out = (float*)d_out;
  char* ws = (char*)d_ws;

  // workspace layout (bytes)
  unsigned short* pro1b = (unsigned short*)(ws + 0);          // 6291456 bf16
  unsigned short* pro2b = (unsigned short*)(ws + 6291456);    // 6291456 bf16
  float* f1 = (float*)(ws + 0);                               // overlays pro (dead after gemm0... used by gemm1)
  unsigned short* wqt = (unsigned short*)(ws + 12582912);     // 1179648
  unsigned short* wkt = (unsigned short*)(ws + 13762560);     // 1179648
  unsigned short* fc1t = (unsigned short*)(ws + 14942208);    // 1179648
  unsigned short* Qb = (unsigned short*)(ws + 16121856);      // 6291456 f16 [bh][s][d]
  unsigned short* Kb = (unsigned short*)(ws + 22413312);      // 6291456 f16
  unsigned short* QT = (unsigned short*)(ws + 28704768);      // 6291456 f16 [bh][d][s]
  unsigned short* KT = (unsigned short*)(ws + 34996224);      // 6291456 f16
  unsigned int* mp2 = (unsigned int*)(ws + 41287680);         // 6291456
  float* f2 = (float*)(ws + 47579136);                        // 12582912
  unsigned short* c1 = (unsigned short*)(ws + 60162048);      // 6291456 bf16
  unsigned short* c2 = (unsigned short*)(ws + 66453504);      // 6291456 bf16
  // total ~72.7 MB

  k_convert<<<3072, 256, 0, stream>>>(pro1, pro1b, 786432);
  k_convert<<<3072, 256, 0, stream>>>(pro2, pro2b, 786432);
  k_transpose<<<dim3(24, 24, 3), 256, 0, stream>>>(WQ, WK, FC1, wqt, wkt, fc1t);
  k_pack<<<dim3(64, BH), 256, 0, stream>>>(mask, mp2);
  k_gemm<<<dim3(64, 6, 2), 256, 0, stream>>>(0, pro1b, pro2b, wqt, wkt,
                                             Qb, Kb, QT, KT, nullptr, nullptr);
  k_attn<<<dim3(16, BH, 2), 256, 0, stream>>>(Qb, Kb, QT, KT, mp2, c1, c2);
  k_gemm<<<dim3(64, 6, 2), 256, 0, stream>>>(1, c1, c2, fc1t, fc1t,
                                             nullptr, nullptr, nullptr, nullptr, f1, f2);
  k_ln<<<8192, 256, 0, stream>>>(f1, f2, g1, b1, g2, b2, out);
}

// Round 7
// 415.604 us; speedup vs baseline: 1.1937x; 1.1937x over previous
//
#include <hip/hip_runtime.h>
#include <hip/hip_bf16.h>
#include <stdint.h>

// Problem constants
#define S 1024
#define DMODEL 768
#define NH 12
#define DK 64
#define BB 4
#define BH 48      // BB*NH
#define M4 4096    // BB*S

typedef __attribute__((ext_vector_type(8))) short bf16x8;
typedef __attribute__((ext_vector_type(4))) float f32x4;
typedef __attribute__((ext_vector_type(4))) _Float16 f16x4;
typedef __attribute__((ext_vector_type(8))) _Float16 f16x8;

static __device__ __forceinline__ unsigned short f2bf(float f) {
  unsigned int u = __float_as_uint(f);
  unsigned int r = u + 0x7FFFu + ((u >> 16) & 1u);   // RNE
  return (unsigned short)(r >> 16);
}
static __device__ __forceinline__ bf16x8 ldfrag(const unsigned short* p) {
  uint4 q = *reinterpret_cast<const uint4*>(p);
  return __builtin_bit_cast(bf16x8, q);
}
static __device__ __forceinline__ f16x8 ldfragh(const unsigned short* p) {
  uint4 q = *reinterpret_cast<const uint4*>(p);
  return __builtin_bit_cast(f16x8, q);
}
static __device__ __forceinline__ unsigned short h2u(_Float16 h) {
  return __builtin_bit_cast(unsigned short, h);
}
// async global->LDS, 16B per lane; LDS dest = wave-uniform base + lane*16
static __device__ __forceinline__ void gl2lds16(const unsigned short* g, unsigned short* l) {
  __builtin_amdgcn_global_load_lds(
      (const __attribute__((address_space(1))) unsigned int*)g,
      (__attribute__((address_space(3))) unsigned int*)l, 16, 0, 0);
}

// ---------------- f32 -> bf16 elementwise convert ----------------
__global__ __launch_bounds__(256) void k_convert(const float* __restrict__ in,
                                                 unsigned short* __restrict__ out, int n4) {
  int i = blockIdx.x * 256 + threadIdx.x;
  if (i < n4) {
    float4 v = reinterpret_cast<const float4*>(in)[i];
    ushort4 o;
    o.x = f2bf(v.x); o.y = f2bf(v.y); o.z = f2bf(v.z); o.w = f2bf(v.w);
    reinterpret_cast<ushort4*>(out)[i] = o;
  }
}

// ---------------- W [k][n] f32 -> Wt [n][k] bf16 (768x768) ----------------
__global__ __launch_bounds__(256) void k_transpose(const float* w0, const float* w1, const float* w2,
                                                   unsigned short* o0, unsigned short* o1, unsigned short* o2) {
  const float* in = blockIdx.z == 0 ? w0 : (blockIdx.z == 1 ? w1 : w2);
  unsigned short* out = blockIdx.z == 0 ? o0 : (blockIdx.z == 1 ? o1 : o2);
  __shared__ float tile[32][33];
  int n0 = blockIdx.x * 32, k0 = blockIdx.y * 32;
  int tid = threadIdx.x;
  int r = tid >> 3, c = (tid & 7) * 4;
  float4 v = *reinterpret_cast<const float4*>(in + (size_t)(k0 + r) * DMODEL + n0 + c);
  tile[r][c] = v.x; tile[r][c + 1] = v.y; tile[r][c + 2] = v.z; tile[r][c + 3] = v.w;
  __syncthreads();
  ushort4 o;
  o.x = f2bf(tile[c + 0][r]);
  o.y = f2bf(tile[c + 1][r]);
  o.z = f2bf(tile[c + 2][r]);
  o.w = f2bf(tile[c + 3][r]);
  *reinterpret_cast<ushort4*>(out + (size_t)(n0 + r) * DMODEL + k0 + c) = o;
}

// ---------------- mask [BH][t][s] int32 -> bit array, direct orientation ----------------
// mp2[bh][wd=s>>5][t] bit(s&31) = mask[t][s].
__global__ __launch_bounds__(256) void k_pack(const int* __restrict__ mask,
                                              unsigned int* __restrict__ mp2) {
  int bh = blockIdx.y;
  int w = threadIdx.x >> 6, lane = threadIdx.x & 63;
  int tile = blockIdx.x * 4 + w;          // 0..255
  int ti = tile >> 4, tj = tile & 15;
  int t0 = ti * 64, s0 = tj * 64;
  const int* mb = mask + (size_t)bh * S * S;
  unsigned long long rowword = 0;
#pragma unroll 8
  for (int r = 0; r < 64; ++r) {
    int v = mb[(size_t)(t0 + r) * S + s0 + lane];
    unsigned long long b = __ballot(v != 0);
    if (lane == r) rowword = b;           // lane r holds bits over s for row t0+r
  }
  unsigned int* p2 = mp2 + (size_t)bh * 32 * S;
  p2[((s0 >> 5) + 0) * S + t0 + lane] = (unsigned int)rowword;
  p2[((s0 >> 5) + 1) * S + t0 + lane] = (unsigned int)(rowword >> 32);
}

// ---------------- 128x128-tile bf16 GEMM, m97-style global_load_lds K-loop ----------------
// LDS unpadded [128][64] shorts; bank conflicts avoided by XOR chunk swizzle on the
// GLOBAL side: LDS[r][c] holds global chunk (c ^ (r&7)); readers index q^(lane15&7).
// mode 0: writes Q/K [BH][S][DK] f16 AND transposed [BH][DK][S] f16.
// mode 1: writes f32 [4096][768] (pre-LayerNorm).
__global__ __launch_bounds__(256, 3) void k_gemm(
    int mode,
    const unsigned short* __restrict__ A0, const unsigned short* __restrict__ A1,
    const unsigned short* __restrict__ Bt0, const unsigned short* __restrict__ Bt1,
    unsigned short* __restrict__ oQ0, unsigned short* __restrict__ oQ1,
    unsigned short* __restrict__ oT0, unsigned short* __restrict__ oT1,
    float* __restrict__ oF0, float* __restrict__ oF1) {
  const unsigned short* A = blockIdx.z ? A1 : A0;
  const unsigned short* Bt = blockIdx.z ? Bt1 : Bt0;
  __shared__ __align__(16) unsigned short As[128 * 64];   // 16384 B, unpadded
  __shared__ __align__(16) unsigned short Bs[128 * 64];   // 16384 B
  int tid = threadIdx.x;
  int m0 = blockIdx.x * 128, n0 = blockIdx.y * 128;
  int w = tid >> 6, lane = tid & 63, lane15 = lane & 15, quad = lane >> 4;
  int row0 = (w >> 1) * 64, col0 = (w & 1) * 64;
  f32x4 acc[4][4] = {};

  // staging addresses: wave w stages rows [w*32, w*32+32) of A and B, 4 insts each
  const unsigned short* gA[4];
  const unsigned short* gB[4];
  unsigned short* lA[4];
  unsigned short* lB[4];
  {
    int lr = lane >> 3;            // row within 8-row inst group
    int ch = lane & 7;             // dest chunk (fixed by HW: lane*16B)
#pragma unroll
    for (int i = 0; i < 4; ++i) {
      int r = w * 32 + i * 8 + lr;            // row in tile
      int cs = ((ch ^ (r & 7)) * 8);          // swizzled source chunk (shorts)
      gA[i] = A + (size_t)(m0 + r) * DMODEL + cs;
      gB[i] = Bt + (size_t)(n0 + r) * DMODEL + cs;
      lA[i] = &As[(w * 32 + i * 8) * 64];
      lB[i] = &Bs[(w * 32 + i * 8) * 64];
    }
  }
  int l7 = lane15 & 7;
#pragma unroll
  for (int i = 0; i < 4; ++i) { gl2lds16(gA[i], lA[i]); gl2lds16(gB[i], lB[i]); }

  for (int kc = 0; kc < 12; ++kc) {
    __syncthreads();   // vmcnt drain: tile kc resident + visible
#pragma unroll
    for (int ks = 0; ks < 2; ++ks) {
      int co = (((ks * 4 + quad) ^ l7) * 8);
      bf16x8 a[4], b[4];
#pragma unroll
      for (int i = 0; i < 4; ++i) a[i] = ldfrag(&As[(row0 + i * 16 + lane15) * 64 + co]);
#pragma unroll
      for (int j = 0; j < 4; ++j) b[j] = ldfrag(&Bs[(col0 + j * 16 + lane15) * 64 + co]);
#pragma unroll
      for (int i = 0; i < 4; ++i)
#pragma unroll
        for (int j = 0; j < 4; ++j)
          acc[i][j] = __builtin_amdgcn_mfma_f32_16x16x32_bf16(a[i], b[j], acc[i][j], 0, 0, 0);
    }
    __syncthreads();   // all reads of tile kc done
    if (kc < 11) {
      int ko = (kc + 1) * 64;
#pragma unroll
      for (int i = 0; i < 4; ++i) { gl2lds16(gA[i] + ko, lA[i]); gl2lds16(gB[i] + ko, lB[i]); }
    }
  }

  if (mode == 0) {
    unsigned short* out = blockIdx.z ? oQ1 : oQ0;
    unsigned short* outT = blockIdx.z ? oT1 : oT0;
    f16x4 iden;
#pragma unroll
    for (int i = 0; i < 4; ++i) iden[i] = (_Float16)((quad * 4 + i) == lane15 ? 1.0f : 0.0f);
    f32x4 zero4 = {};
#pragma unroll
    for (int i = 0; i < 4; ++i)
#pragma unroll
      for (int j = 0; j < 4; ++j) {
        f16x4 cf;
#pragma unroll
        for (int reg = 0; reg < 4; ++reg) cf[reg] = (_Float16)acc[i][j][reg];
        f32x4 tq = __builtin_amdgcn_mfma_f32_16x16x16f16(cf, iden, zero4, 0, 0, 0);
        {   // Qb store: tq regs = 4 consecutive d, fixed s -> ushort4
          int m = m0 + row0 + i * 16 + lane15;
          int n = n0 + col0 + j * 16 + quad * 4;
          int b = m >> 10, s = m & 1023, h = n >> 6, d = n & 63;
          ushort4 o;
          o.x = h2u((_Float16)tq[0]); o.y = h2u((_Float16)tq[1]);
          o.z = h2u((_Float16)tq[2]); o.w = h2u((_Float16)tq[3]);
          *reinterpret_cast<ushort4*>(&out[(((size_t)(b * NH + h)) * S + s) * DK + d]) = o;
        }
        {   // QT store: acc regs = 4 consecutive s, fixed d -> ushort4
          int n = n0 + col0 + j * 16 + lane15;
          int m = m0 + row0 + i * 16 + quad * 4;
          int b = m >> 10, s = m & 1023, h = n >> 6, d = n & 63;
          ushort4 o;
          o.x = h2u((_Float16)acc[i][j][0]); o.y = h2u((_Float16)acc[i][j][1]);
          o.z = h2u((_Float16)acc[i][j][2]); o.w = h2u((_Float16)acc[i][j][3]);
          *reinterpret_cast<ushort4*>(&outT[(((size_t)(b * NH + h)) * DK + d) * S + s]) = o;
        }
      }
  } else {
    float* out = blockIdx.z ? oF1 : oF0;
#pragma unroll
    for (int i = 0; i < 4; ++i)
#pragma unroll
      for (int j = 0; j < 4; ++j)
#pragma unroll
        for (int reg = 0; reg < 4; ++reg) {
          int m = m0 + row0 + i * 16 + quad * 4 + reg;
          int n = n0 + col0 + j * 16 + lane15;
          out[(size_t)m * DMODEL + n] = acc[i][j][reg];
        }
  }
}

// ---------------- fused dual-path attention: operand-swapped S^T, no P round-trip ----------------
// (R5 version — best measured.) Block = (bh, path, 128 rows); wave w owns rows
// [s0b+w*32,+32). Per 64-j chunk: stage Y [j][d] + YT [d][j] (f16) + mask words.
// QK: S^T frags via mfma(A=Ychunk, B=Xfrag); exp w/o max (masked -> exact 0);
// P^T frag feeds PV (16x16x16 f16) directly.
__global__ __launch_bounds__(256, 3) void k_attn(
    const unsigned short* __restrict__ Qb, const unsigned short* __restrict__ Kb,
    const unsigned short* __restrict__ QT, const unsigned short* __restrict__ KT,
    const unsigned int* __restrict__ mp2,
    unsigned short* __restrict__ c1, unsigned short* __restrict__ c2) {
  int bh = blockIdx.y, path = blockIdx.z;
  int s0b = blockIdx.x * 128;
  const unsigned short* X = path ? Kb : Qb;
  const unsigned short* Y = path ? Qb : Kb;
  const unsigned short* YT = path ? QT : KT;
  unsigned short* outc = path ? c2 : c1;

  __shared__ __align__(16) unsigned short YS[64 * 72];    // Y chunk [j][d] f16
  __shared__ __align__(16) unsigned short YTS[64 * 72];   // YT chunk [d][j] f16
  __shared__ unsigned int MWS[256];                       // mask words for this chunk

  const unsigned short* Xb = X + (size_t)bh * S * DK;
  const unsigned short* Yb = Y + (size_t)bh * S * DK;
  const unsigned short* YTb = YT + (size_t)bh * DK * S;
  const unsigned int* mbg = mp2 + (size_t)bh * 32 * S;

  int tid = threadIdx.x;
  int w = tid >> 6, lane = tid & 63, lane15 = lane & 15, quad = lane >> 4;
  int s0w = s0b + w * 32;

  // X fragments double as MFMA B-operands (B[k=d][n=s]) for the swapped QK
  f16x8 xf[2][2];
#pragma unroll
  for (int rg = 0; rg < 2; ++rg) {
    xf[rg][0] = ldfragh(Xb + (size_t)(s0w + rg * 16 + lane15) * DK + quad * 8);
    xf[rg][1] = ldfragh(Xb + (size_t)(s0w + rg * 16 + lane15) * DK + 32 + quad * 8);
  }

  // staging: thread covers row sr4 (0..63), 16 cols at sc4
  int sr4 = tid >> 2, sc4 = (tid & 3) * 16;
  const unsigned short* gY = Yb + (size_t)sr4 * DK + sc4;
  const unsigned short* gYT = YTb + (size_t)sr4 * S + sc4;
  uint4 y0 = *reinterpret_cast<const uint4*>(gY);
  uint4 y1 = *reinterpret_cast<const uint4*>(gY + 8);
  uint4 t0 = *reinterpret_cast<const uint4*>(gYT);
  uint4 t1 = *reinterpret_cast<const uint4*>(gYT + 8);
  // mask-word prefetch (both paths read mp2 direct orientation)
  int mws_idx = (path == 0) ? ((tid & 63) * 4 + (tid >> 6)) : ((tid & 127) * 2 + (tid >> 7));
  unsigned int mwv = (path == 0)
      ? mbg[((size_t)((s0b >> 5) + (tid >> 6))) * S + (tid & 63)]
      : mbg[((size_t)(tid >> 7)) * S + s0b + (tid & 127)];

  f32x4 outa[2][4] = {};
  float lsum[2] = {0.f, 0.f};

  for (int jc = 0; jc < 16; ++jc) {
    __syncthreads();   // prior chunk frag reads complete
    *reinterpret_cast<uint4*>(&YS[sr4 * 72 + sc4]) = y0;
    *reinterpret_cast<uint4*>(&YS[sr4 * 72 + sc4 + 8]) = y1;
    *reinterpret_cast<uint4*>(&YTS[sr4 * 72 + sc4]) = t0;
    *reinterpret_cast<uint4*>(&YTS[sr4 * 72 + sc4 + 8]) = t1;
    MWS[mws_idx] = mwv;
    {
      int jn = (jc + 1 < 16) ? (jc + 1) * 64 : jc * 64;   // clamped prefetch
      y0 = *reinterpret_cast<const uint4*>(gY + (size_t)jn * DK);
      y1 = *reinterpret_cast<const uint4*>(gY + (size_t)jn * DK + 8);
      t0 = *reinterpret_cast<const uint4*>(gYT + jn);
      t1 = *reinterpret_cast<const uint4*>(gYT + jn + 8);
      mwv = (path == 0)
          ? mbg[((size_t)((s0b >> 5) + (tid >> 6))) * S + jn + (tid & 63)]
          : mbg[((size_t)((jn >> 5) + (tid >> 7))) * S + s0b + (tid & 127)];
    }
    __syncthreads();   // staging visible

    // swapped QK: S^T[j][s] frags, C(row=j=quad*4+reg, col=s=lane15)
    f32x4 scv[4][2];
#pragma unroll
    for (int st = 0; st < 4; ++st) {
      f16x8 a0 = ldfragh(&YS[(st * 16 + lane15) * 72 + quad * 8]);
      f16x8 a1 = ldfragh(&YS[(st * 16 + lane15) * 72 + 32 + quad * 8]);
#pragma unroll
      for (int rg = 0; rg < 2; ++rg) {
        f32x4 v = {};
        v = __builtin_amdgcn_mfma_f32_16x16x32_f16(a0, xf[rg][0], v, 0, 0, 0);
        v = __builtin_amdgcn_mfma_f32_16x16x32_f16(a1, xf[rg][1], v, 0, 0, 0);
        scv[st][rg] = v;
      }
    }
    // mask + exp; P^T frags are directly x16 A-operands
    f16x4 pfa[4][2];
    if (path == 0) {
#pragma unroll
      for (int st = 0; st < 4; ++st)
#pragma unroll
        for (int reg = 0; reg < 4; ++reg) {
          unsigned int wdv = MWS[(st * 16 + quad * 4 + reg) * 4 + w];
#pragma unroll
          for (int rg = 0; rg < 2; ++rg) {
            float e = __expf(scv[st][rg][reg] * 0.125f);
            float p = ((wdv >> (unsigned)(rg * 16 + lane15)) & 1u) ? 0.f : e;
            lsum[rg] += p;
            pfa[st][rg][reg] = (_Float16)p;
          }
        }
    } else {
#pragma unroll
      for (int rg = 0; rg < 2; ++rg) {
        unsigned int wv0 = MWS[(w * 32 + rg * 16 + lane15) * 2 + 0];
        unsigned int wv1 = MWS[(w * 32 + rg * 16 + lane15) * 2 + 1];
#pragma unroll
        for (int st = 0; st < 4; ++st) {
          unsigned int wdv = (st < 2) ? wv0 : wv1;
#pragma unroll
          for (int reg = 0; reg < 4; ++reg) {
            unsigned int sh = (unsigned)((st & 1) * 16 + quad * 4 + reg);
            float e = __expf(scv[st][rg][reg] * 0.125f);
            float p = ((wdv >> sh) & 1u) ? 0.f : e;
            lsum[rg] += p;
            pfa[st][rg][reg] = (_Float16)p;
          }
        }
      }
    }
    // PV: outa[rg][dsub] += P^T_frag (A) x Y (B from YTS, b64 reads)
#pragma unroll
    for (int st = 0; st < 4; ++st)
#pragma unroll
      for (int dsub = 0; dsub < 4; ++dsub) {
        uint2 q = *reinterpret_cast<const uint2*>(&YTS[(dsub * 16 + lane15) * 72 + st * 16 + quad * 4]);
        f16x4 yb = __builtin_bit_cast(f16x4, q);
#pragma unroll
        for (int rg = 0; rg < 2; ++rg)
          outa[rg][dsub] = __builtin_amdgcn_mfma_f32_16x16x16f16(pfa[st][rg], yb, outa[rg][dsub], 0, 0, 0);
      }
  }

  // row sums: lane holds partial for row (rg, lane15) over its j cols; reduce across quads
#pragma unroll
  for (int rg = 0; rg < 2; ++rg) {
    lsum[rg] += __shfl_xor(lsum[rg], 16);
    lsum[rg] += __shfl_xor(lsum[rg], 32);
  }
  float rinv[2][4];
#pragma unroll
  for (int rg = 0; rg < 2; ++rg)
#pragma unroll
    for (int reg = 0; reg < 4; ++reg)
      rinv[rg][reg] = 1.0f / __shfl(lsum[rg], quad * 4 + reg);

  int b = bh / NH, h = bh % NH;
#pragma unroll
  for (int rg = 0; rg < 2; ++rg)
#pragma unroll
    for (int dsub = 0; dsub < 4; ++dsub)
#pragma unroll
      for (int reg = 0; reg < 4; ++reg) {
        float v = outa[rg][dsub][reg] * rinv[rg][reg];
        int srow = s0w + rg * 16 + quad * 4 + reg;
        size_t idx = ((size_t)(b * S) + srow) * DMODEL + h * DK + dsub * 16 + lane15;
        outc[idx] = f2bf(v);
      }
}

// ---------------- LayerNorm over 768, one block per row ----------------
__global__ __launch_bounds__(256) void k_ln(const float* __restrict__ f1, const float* __restrict__ f2,
                                            const float* __restrict__ g1, const float* __restrict__ b1,
                                            const float* __restrict__ g2, const float* __restrict__ b2,
                                            float* __restrict__ out) {
  int rowg = blockIdx.x;
  int sel = rowg >> 12;
  int row = rowg & 4095;
  const float* in = sel ? f2 : f1;
  const float* g = sel ? g2 : g1;
  const float* be = sel ? b2 : b1;
  int tid = threadIdx.x;
  const float* p = in + (size_t)row * DMODEL;
  float x0 = p[tid], x1 = p[tid + 256], x2 = p[tid + 512];
  float s = x0 + x1 + x2;
  float ss = x0 * x0 + x1 * x1 + x2 * x2;
#pragma unroll
  for (int m = 1; m < 64; m <<= 1) { s += __shfl_xor(s, m); ss += __shfl_xor(ss, m); }
  __shared__ float ps[4], pss[4];
  int w = tid >> 6;
  if ((tid & 63) == 0) { ps[w] = s; pss[w] = ss; }
  __syncthreads();
  s = ps[0] + ps[1] + ps[2] + ps[3];
  ss = pss[0] + pss[1] + pss[2] + pss[3];
  float mu = s * (1.0f / 768.0f);
  float var = ss * (1.0f / 768.0f) - mu * mu;
  float rstd = rsqrtf(var + 1e-5f);
  float* o = out + ((size_t)sel * M4 + row) * DMODEL;
  o[tid] = (x0 - mu) * rstd * g[tid] + be[tid];
  o[tid + 256] = (x1 - mu) * rstd * g[tid + 256] + be[tid + 256];
  o[tid + 512] = (x2 - mu) * rstd * g[tid + 512] + be[tid + 512];
}

extern "C" void kernel_launch(void* const* d_in, const int* in_sizes, int n_in,
                              void* d_out, int out_size, void* d_ws, size_t ws_size,
                              hipStream_t stream) {
  const float* pro1 = (const float*)d_in[0];
  const float* pro2 = (const float*)d_in[1];
  const int* mask = (const int*)d_in[2];
  const float* WQ = (const float*)d_in[3];
  const float* WK = (const float*)d_in[4];
  const float* FC1 = (const float*)d_in[5];
  const float* g1 = (const float*)d_in[6];
  const float* b1 = (const float*)d_in[7];
  const float* g2 = (const float*)d_in[8];
  const float* b2 = (const float*)d_in[9];
  float* out = (float*)d_out;
  char* ws = (char*)d_ws;

  // workspace layout (bytes)
  unsigned short* pro1b = (unsigned short*)(ws + 0);          // 6291456 bf16
  unsigned short* pro2b = (unsigned short*)(ws + 6291456);    // 6291456 bf16
  float* f1 = (float*)(ws + 0);                               // overlays pro (dead by gemm1)
  unsigned short* wqt = (unsigned short*)(ws + 12582912);     // 1179648
  unsigned short* wkt = (unsigned short*)(ws + 13762560);     // 1179648
  unsigned short* fc1t = (unsigned short*)(ws + 14942208);    // 1179648
  unsigned short* Qb = (unsigned short*)(ws + 16121856);      // 6291456 f16 [bh][s][d]
  unsigned short* Kb = (unsigned short*)(ws + 22413312);      // 6291456 f16
  unsigned short* QT = (unsigned short*)(ws + 28704768);      // 6291456 f16 [bh][d][s]
  unsigned short* KT = (unsigned short*)(ws + 34996224);      // 6291456 f16
  unsigned int* mp2 = (unsigned int*)(ws + 41287680);         // 6291456
  float* f2 = (float*)(ws + 47579136);                        // 12582912
  unsigned short* c1 = (unsigned short*)(ws + 60162048);      // 6291456 bf16
  unsigned short* c2 = (unsigned short*)(ws + 66453504);      // 6291456 bf16
  // total ~72.7 MB

  k_convert<<<3072, 256, 0, stream>>>(pro1, pro1b, 786432);
  k_convert<<<3072, 256, 0, stream>>>(pro2, pro2b, 786432);
  k_transpose<<<dim3(24, 24, 3), 256, 0, stream>>>(WQ, WK, FC1, wqt, wkt, fc1t);
  k_pack<<<dim3(64, BH), 256, 0, stream>>>(mask, mp2);
  k_gemm<<<dim3(32, 6, 2), 256, 0, stream>>>(0, pro1b, pro2b, wqt, wkt,
                                             Qb, Kb, QT, KT, nullptr, nullptr);
  k_attn<<<dim3(8, BH, 2), 256, 0, stream>>>(Qb, Kb, QT, KT, mp2, c1, c2);
  k_gemm<<<dim3(32, 6, 2), 256, 0, stream>>>(1, c1, c2, fc1t, fc1t,
                                             nullptr, nullptr, nullptr, nullptr, f1, f2);
  k_ln<<<8192, 256, 0, stream>>>(f1, f2, g1, b1, g2, b2, out);
}